// Round 9
// baseline (103.282 us; speedup 1.0000x reference)
//
#include <hip/hip_runtime.h>

// KAN conv as densified GEMM: out[px,f] = sum_k Basis[px,k] * W[k,f]
//   px = (b,p,q) 8192, f = 64. K = 32 chunks x 320 cols (2 channels each):
//     kl in [0,288):   spline (cl*144 + ij*16 + g), taps (1-fr)@idx, fr@idx+1
//     kl in [288,306): silu at cl*9 + ij
//     kl in [306,320): zero pad (W rows 0)
// W pre-swizzled to MFMA 16x16x32 f16 B-fragment order.
// This round: M=64 per WG (2 image rows), waves split M (16 px each) so all 4
// waves read the SAME B-fragments (L1 dedup) -> unique L2 W-bytes halved; no
// cross-wave reduction. Per-WG chunk-order rotation de-lockfsteps the L2
// slices. 6-way K-split -> partials + combine. No atomics, no memset.

typedef _Float16 v8h __attribute__((ext_vector_type(8)));
typedef float    v4f __attribute__((ext_vector_type(4)));

#define NSLOT   655360            // 10240 * 64 f16
#define PARTOFF 1310720           // bytes: wsw size
#define NPART   524288            // floats per partial (8192*64)

// Wsw slot ((ks*4+nt)*64+lane)*8+j = W[k=ks*32+(lane>>4)*8+j][f=nt*16+(lane&15)]
__global__ __launch_bounds__(256) void prep_wsw(const float* __restrict__ cp,
                                                const float* __restrict__ w1,
                                                const float* __restrict__ w2,
                                                _Float16* __restrict__ wsw) {
    int tid  = blockIdx.x * 256 + threadIdx.x;
    int j    = tid & 7;
    int lane = (tid >> 3) & 63;
    int rest = tid >> 9;
    int nt   = rest & 3;
    int ks   = rest >> 2;                    // global kstep 0..319
    int k    = ks * 32 + ((lane >> 4) << 3) + j;
    int f    = (nt << 4) + (lane & 15);
    int chunk = k / 320;
    int kl    = k - chunk * 320;
    float val = 0.f;
    if (kl < 288) {
        int cl = kl / 144;
        int r  = kl - cl * 144;              // ij*16 + g
        int c  = chunk * 2 + cl;
        val = w1[f * 576 + c * 9 + (r >> 4)] * cp[f * 9216 + c * 144 + r];
    } else if (kl < 306) {
        int i2 = kl - 288;
        int cl = i2 / 9;
        int ij = i2 - cl * 9;
        int c  = chunk * 2 + cl;
        val = w2[f * 576 + c * 9 + ij];
    }
    wsw[tid] = (_Float16)val;
}

// grid 768: kh = blk>>7 (6 K-splits of {6,6,5,5,5,5} chunks), mb = blk&127
// (64-px M-block = 2 image rows). Wave wv owns px [wv*16, wv*16+16), all
// ksteps of each chunk; B-fragments identical across waves -> L1 dedup.
__global__ __launch_bounds__(256, 3) void kan_mfma(const float* __restrict__ x,
                                                   const _Float16* __restrict__ wsw,
                                                   float* __restrict__ part) {
    __shared__ __align__(16) _Float16 sb[64 * 328];   // 41984 B; stride 328 breaks banks

    int blk = blockIdx.x;
    int kh  = blk >> 7;
    int mb  = blk & 127;
    int b     = mb >> 4;
    int prow0 = (mb & 15) << 1;
    int t = threadIdx.x, wv = t >> 6, lane = t & 63;
    int m = lane & 15, kq = lane >> 4;

    const int chs[7] = {0, 6, 12, 17, 22, 27, 32};
    int ch0 = chs[kh], ch1 = chs[kh + 1];
    int nch = ch1 - ch0;
    int rot = mb % nch;                      // de-lockstep chunk order

    // one-time zero (pad cols + silu holes; spline/silu slots overwritten per chunk)
    v4f z4 = (v4f){0.f, 0.f, 0.f, 0.f};
    for (int i4 = t; i4 < 2624; i4 += 256) ((v4f*)sb)[i4] = z4;

    // ---- hoist per-thread event geometry (chunk-invariant) ----
    int  off0[5], sbF[5], sil[5];
    bool okv[5];
#pragma unroll
    for (int it = 0; it < 5; ++it) {
        int e  = t + it * 256;
        int ec = e < 1152 ? e : 0;
        int px = ec / 18;
        int r  = ec - px * 18;
        int cl = r / 9;
        int ij = r - cl * 9;
        int di = ij / 3;
        int dj = ij - di * 3;
        int p   = prow0 + (px >> 5);
        int q   = px & 31;
        int row = p + di - 1;
        int col = q + dj - 1;
        okv[it]  = ((unsigned)row < 32u) && ((unsigned)col < 32u) && (e < 1152);
        off0[it] = okv[it] ? (((b * 32 + row) * 32 + col) * 64 + cl) : 0;
        sbF[it]  = px * 328 + cl * 144 + ij * 16;
        sil[it]  = px * 328 + 288 + cl * 9 + ij;
    }

    v4f acc[4];
#pragma unroll
    for (int n = 0; n < 4; ++n) acc[n] = z4;

    // prologue x prefetch for first chunk (channel stride 2 per chunk)
    int gch0 = ch0 + rot;
    if (gch0 >= ch1) gch0 -= nch;
    float vbuf[5];
#pragma unroll
    for (int it = 0; it < 5; ++it)
        vbuf[it] = okv[it] ? x[off0[it] + gch0 * 2] : 0.f;

    __syncthreads();   // zero done

    int gch = gch0;
    for (int ci = 0; ci < nch; ++ci) {
        // ---- scatter: build 16-f16 one-hot-pair row in v8h regs, 2x b128 ----
#pragma unroll
        for (int it = 0; it < 5; ++it) {
            if (t + it * 256 < 1152) {       // wave-uniform boundary
                float v  = vbuf[it];
                float xc = fminf(fmaxf(v, -1.f), 1.f);
                float tt = (xc + 1.f) * 7.5f;
                int idx  = (int)tt;
                if (idx > 14) idx = 14;
                float fr = tt - (float)idx;
                float sv = v * __builtin_amdgcn_rcpf(1.f + __expf(-v));
                _Float16 hg = (_Float16)(1.f - fr);
                _Float16 hf = (_Float16)fr;
                _Float16 hz = (_Float16)0.f;
                v8h row0, row1;
#pragma unroll
                for (int g = 0; g < 8; ++g)
                    row0[g] = (g == idx) ? hg : ((g == idx + 1) ? hf : hz);
#pragma unroll
                for (int g = 8; g < 16; ++g)
                    row1[g - 8] = (g == idx) ? hg : ((g == idx + 1) ? hf : hz);
                *(v8h*)(sb + sbF[it])     = row0;
                *(v8h*)(sb + sbF[it] + 8) = row1;
                sb[sil[it]] = (_Float16)sv;
            }
        }
        // ---- prefetch next chunk's x ----
        int gnx = gch + 1;
        if (gnx >= ch1) gnx = ch0;
        if (ci + 1 < nch) {
#pragma unroll
            for (int it = 0; it < 5; ++it)
                vbuf[it] = okv[it] ? x[off0[it] + gnx * 2] : 0.f;
        }
        __syncthreads();
        // ---- MFMA: 10 ksteps, wave does ALL of them for its 16 px ----
        const _Float16* ap0 = sb + (wv * 16 + m) * 328 + kq * 8;
        const v8h* bp = (const v8h*)wsw + (size_t)(gch * 10) * 256 + lane;
#pragma unroll
        for (int s = 0; s < 10; ++s) {
            v8h a = *(const v8h*)(ap0 + s * 32);
            acc[0] = __builtin_amdgcn_mfma_f32_16x16x32_f16(a, bp[s * 256],       acc[0], 0, 0, 0);
            acc[1] = __builtin_amdgcn_mfma_f32_16x16x32_f16(a, bp[s * 256 + 64],  acc[1], 0, 0, 0);
            acc[2] = __builtin_amdgcn_mfma_f32_16x16x32_f16(a, bp[s * 256 + 128], acc[2], 0, 0, 0);
            acc[3] = __builtin_amdgcn_mfma_f32_16x16x32_f16(a, bp[s * 256 + 192], acc[3], 0, 0, 0);
        }
        __syncthreads();
        gch = gnx;
    }

    // ---- epilogue: wave owns its px rows, direct stores (no reduction) ----
    float* op = part + (size_t)kh * NPART + (size_t)(mb * 64) * 64;
#pragma unroll
    for (int nt = 0; nt < 4; ++nt)
#pragma unroll
        for (int r = 0; r < 4; ++r) {
            int px = wv * 16 + kq * 4 + r;   // C/D: row=(lane>>4)*4+reg
            int f  = nt * 16 + m;            //      col=lane&15
            op[px * 64 + f] = acc[nt][r];
        }
}

__global__ __launch_bounds__(256) void combine(const float* __restrict__ part,
                                               float* __restrict__ out) {
    int i = blockIdx.x * 256 + threadIdx.x;
    v4f s = ((const v4f*)part)[i];
#pragma unroll
    for (int kh = 1; kh < 6; ++kh)
        s += ((const v4f*)(part + (size_t)kh * NPART))[i];
    ((v4f*)out)[i] = s;
}

extern "C" void kernel_launch(void* const* d_in, const int* in_sizes, int n_in,
                              void* d_out, int out_size, void* d_ws, size_t ws_size,
                              hipStream_t stream) {
    const float* x  = (const float*)d_in[0];
    const float* cp = (const float*)d_in[1];
    const float* w1 = (const float*)d_in[2];
    const float* w2 = (const float*)d_in[3];
    _Float16* wsw = (_Float16*)d_ws;                       // 1.31 MB
    float*    prt = (float*)((char*)d_ws + PARTOFF);       // 6 x 2 MB partials

    prep_wsw<<<NSLOT / 256, 256, 0, stream>>>(cp, w1, w2, wsw);
    kan_mfma<<<768, 256, 0, stream>>>(x, wsw, prt);
    combine<<<512, 256, 0, stream>>>(prt, (float*)d_out);
}